// Round 11
// baseline (542.229 us; speedup 1.0000x reference)
//
#include <hip/hip_runtime.h>
#include <hip/hip_bf16.h>

#define N_TOK 2048
#define HIDDEN 1024
#define NHEAD 16
#define DHEAD 64

typedef __attribute__((ext_vector_type(8))) short bf16x8;
typedef __attribute__((ext_vector_type(4))) float f32x4;

#define WAITV(N) do { asm volatile("s_waitcnt vmcnt(" #N ")" ::: "memory"); \
                      __builtin_amdgcn_sched_barrier(0); } while (0)
#define LGKM0() do { asm volatile("s_waitcnt lgkmcnt(0)" ::: "memory"); \
                     __builtin_amdgcn_sched_barrier(0); } while (0)

__device__ inline unsigned short f2bf(float x) {
    __hip_bfloat16 h = __float2bfloat16(x);
    return *reinterpret_cast<unsigned short*>(&h);
}

__device__ inline f32x4 zero4() {
    f32x4 z;
    z[0] = 0.f; z[1] = 0.f; z[2] = 0.f; z[3] = 0.f;
    return z;
}

// async global->LDS, 16B per lane; dest = uniform base + lane*16
__device__ inline void gl_lds16(const unsigned short* g, unsigned short* l) {
    __builtin_amdgcn_global_load_lds(
        (const __attribute__((address_space(1))) unsigned int*)g,
        (__attribute__((address_space(3))) unsigned int*)l, 16, 0, 0);
}

// ---------------- K0: fused f32 -> bf16 conversion for x, Wq, Wk, Wv ----------------
__global__ void cvt4_kernel(const float* __restrict__ x, const float* __restrict__ wq,
                            const float* __restrict__ wk, const float* __restrict__ wv,
                            unsigned short* __restrict__ dst) {
    int i = blockIdx.x * blockDim.x + threadIdx.x;  // 1310720 float4 jobs
    const float* src;
    int off;
    if (i < 524288)       { src = x;  off = i; }
    else if (i < 786432)  { src = wq; off = i - 524288; }
    else if (i < 1048576) { src = wk; off = i - 786432; }
    else                  { src = wv; off = i - 1048576; }
    float4 v = reinterpret_cast<const float4*>(src)[off];
    ushort4 o;
    o.x = f2bf(v.x); o.y = f2bf(v.y); o.z = f2bf(v.z); o.w = f2bf(v.w);
    reinterpret_cast<ushort4*>(dst)[i] = o;
}

// ---------------- K1: fused QKV GEMM; v-region writes tiled vt directly ----------------
__launch_bounds__(256)
__global__ void gemm_qkv(const unsigned short* __restrict__ xb,
                         const unsigned short* __restrict__ wb,
                         const float* __restrict__ bq, const float* __restrict__ bk,
                         const float* __restrict__ bv,
                         unsigned short* __restrict__ qb, unsigned short* __restrict__ kb,
                         unsigned short* __restrict__ vt) {
    __shared__ unsigned short As[2][128 * 64];
    __shared__ unsigned short Bs[2][128 * 64];
    const int tid = threadIdx.x;
    const int lane = tid & 63;
    const int w = tid >> 6;
    const int wr = w >> 1, wc = w & 1;
    const int rb = blockIdx.y * 128;
    const int cb = blockIdx.x * 128;
    const int r0 = tid >> 3, c0 = tid & 7;

    f32x4 acc[4][4];
    for (int i = 0; i < 4; i++)
        for (int j = 0; j < 4; j++) acc[i][j] = zero4();

    uint4 va[4], vb4[4];
#pragma unroll
    for (int i = 0; i < 4; i++) {
        va[i]  = *reinterpret_cast<const uint4*>(xb + (size_t)(rb + r0 + 32 * i) * HIDDEN + c0 * 8);
        vb4[i] = *reinterpret_cast<const uint4*>(wb + (size_t)(cb + r0 + 32 * i) * HIDDEN + c0 * 8);
    }
#pragma unroll
    for (int i = 0; i < 4; i++) {
        int row = r0 + 32 * i;
        *reinterpret_cast<uint4*>(As[0] + row * 64 + ((c0 ^ (row & 7)) << 3)) = va[i];
        *reinterpret_cast<uint4*>(Bs[0] + row * 64 + ((c0 ^ (row & 7)) << 3)) = vb4[i];
    }
    __syncthreads();
    int cur = 0;

    for (int kt = 0; kt < 16; ++kt) {
        if (kt < 15) {
#pragma unroll
            for (int i = 0; i < 4; i++) {
                va[i]  = *reinterpret_cast<const uint4*>(xb + (size_t)(rb + r0 + 32 * i) * HIDDEN + (kt + 1) * 64 + c0 * 8);
                vb4[i] = *reinterpret_cast<const uint4*>(wb + (size_t)(cb + r0 + 32 * i) * HIDDEN + (kt + 1) * 64 + c0 * 8);
            }
        }
#pragma unroll
        for (int kk = 0; kk < 2; kk++) {
            bf16x8 a[4], b[4];
#pragma unroll
            for (int mi = 0; mi < 4; mi++) {
                int row = wr * 64 + mi * 16 + (lane & 15);
                a[mi] = *reinterpret_cast<const bf16x8*>(As[cur] + row * 64 + (((kk * 4 + (lane >> 4)) ^ (row & 7)) << 3));
            }
#pragma unroll
            for (int ni = 0; ni < 4; ni++) {
                int row = wc * 64 + ni * 16 + (lane & 15);
                b[ni] = *reinterpret_cast<const bf16x8*>(Bs[cur] + row * 64 + (((kk * 4 + (lane >> 4)) ^ (row & 7)) << 3));
            }
#pragma unroll
            for (int mi = 0; mi < 4; mi++)
#pragma unroll
                for (int ni = 0; ni < 4; ni++)
                    acc[mi][ni] = __builtin_amdgcn_mfma_f32_16x16x32_bf16(a[mi], b[ni], acc[mi][ni], 0, 0, 0);
        }
        if (kt < 15) {
#pragma unroll
            for (int i = 0; i < 4; i++) {
                int row = r0 + 32 * i;
                *reinterpret_cast<uint4*>(As[cur ^ 1] + row * 64 + ((c0 ^ (row & 7)) << 3)) = va[i];
                *reinterpret_cast<uint4*>(Bs[cur ^ 1] + row * 64 + ((c0 ^ (row & 7)) << 3)) = vb4[i];
            }
        }
        __syncthreads();
        cur ^= 1;
    }

    const int region = blockIdx.x >> 3;  // 0=q, 1=k, 2=v
    const float* bias = region == 0 ? bq : (region == 1 ? bk : bv);
    unsigned short* dst = region == 0 ? qb : kb;
#pragma unroll
    for (int mi = 0; mi < 4; mi++) {
#pragma unroll
        for (int ni = 0; ni < 4; ni++) {
            int colg = cb + wc * 64 + ni * 16 + (lane & 15);
            int jj = colg & 1023;
            int hh = jj >> 6, d = jj & 63;
            float bval = bias[jj];
#pragma unroll
            for (int r = 0; r < 4; r++) {
                int n = rb + wr * 64 + mi * 16 + ((lane >> 4) << 2) + r;
                unsigned short val = f2bf(acc[mi][ni][r] + bval);
                if (region < 2)
                    dst[((size_t)hh * N_TOK + n) * 64 + d] = val;
                else  // v: tiled layout vt[((h*64 + n/32)*64 + d)*32 + n%32]
                    vt[(((size_t)(hh * 64 + (n >> 5)) * 64 + d) * 32) + (n & 31)] = val;
            }
        }
    }
}

// ---------------- K2a: stats — chunked (512 cols), K dbuf, counted vmcnt ----------------
// grid 8192 x 64 threads; block = (h, rb, chunk); LDS 8KB -> ~20 blocks/CU.
__launch_bounds__(64, 4)
__global__ void attn_stats(const unsigned short* __restrict__ qb,
                           const unsigned short* __restrict__ kb,
                           const float* __restrict__ hist,
                           const float* __restrict__ beta_p,
                           float* __restrict__ m_part,
                           float* __restrict__ l_part) {
    __shared__ unsigned short Kbuf[2][2048];
    const int lane = threadIdx.x;
    const int g = lane >> 4, q15 = lane & 15;
    const int bid = blockIdx.x;
    const int orig = (bid & 7) * 1024 + (bid >> 3);   // XCD swizzle: 2 heads per XCD
    const int h = orig >> 9;
    const int rb = (orig >> 2) & 127;
    const int chunk = orig & 3;
    const float beta = beta_p[0];
    const float scale = 0.125f;

    const unsigned short* qsrc = qb + ((size_t)h * N_TOK + rb * 16 + q15) * 64;
    bf16x8 aq0 = *reinterpret_cast<const bf16x8*>(qsrc + 8 * g);
    bf16x8 aq1 = *reinterpret_cast<const bf16x8*>(qsrc + 8 * g + 32);

    const int koff = (lane >> 3) * 64 + (((lane & 7) ^ (lane >> 3)) << 3);
    const unsigned short* kt0 = kb + (size_t)h * N_TOK * 64;

#define STAGE_K2(CT, B) do { const unsigned short* _s = kt0 + (size_t)(CT) * 2048 + koff; \
        gl_lds16(_s,        &Kbuf[B][0]);    gl_lds16(_s + 512,  &Kbuf[B][512]);   \
        gl_lds16(_s + 1024, &Kbuf[B][1024]); gl_lds16(_s + 1536, &Kbuf[B][1536]); } while (0)

    const size_t rowbase = ((size_t)h * N_TOK + rb * 16 + q15) * N_TOK;
    const float* hbase = hist + rowbase + chunk * 512 + 4 * g;
    const int ct0 = chunk * 16;

    float m = -1e30f, l = 0.0f;
    f32x4 h4[2][2];

    STAGE_K2(ct0, 0);
    h4[0][0] = *reinterpret_cast<const f32x4*>(hbase);
    h4[0][1] = *reinterpret_cast<const f32x4*>(hbase + 16);
    h4[1][0] = *reinterpret_cast<const f32x4*>(hbase + 32);
    h4[1][1] = *reinterpret_cast<const f32x4*>(hbase + 48);

#pragma unroll 2
    for (int t = 0; t < 16; ++t) {
        const int cur = t & 1;
        const int tn = (t < 15) ? (t + 1) : 15;
        STAGE_K2(ct0 + tn, tn & 1);
        WAITV(6);  // retire stage(t)+hist(t); keep stage(t+1)+hist(t+1)
        f32x4 s_acc[2];
#pragma unroll
        for (int nt = 0; nt < 2; ++nt) {
            int krow = nt * 16 + q15;
            bf16x8 kf0 = *reinterpret_cast<const bf16x8*>(Kbuf[cur] + krow * 64 + ((g ^ (q15 & 7)) << 3));
            bf16x8 kf1 = *reinterpret_cast<const bf16x8*>(Kbuf[cur] + krow * 64 + (((4 + g) ^ (q15 & 7)) << 3));
            s_acc[nt] = __builtin_amdgcn_mfma_f32_16x16x32_bf16(kf0, aq0, zero4(), 0, 0, 0);
            s_acc[nt] = __builtin_amdgcn_mfma_f32_16x16x32_bf16(kf1, aq1, s_acc[nt], 0, 0, 0);
        }
        float sc[2][4];
#pragma unroll
        for (int nt = 0; nt < 2; ++nt)
#pragma unroll
            for (int r = 0; r < 4; ++r)
                sc[nt][r] = s_acc[nt][r] * scale + beta * h4[cur][nt][r];

        // re-issue hist(t+2) into the just-consumed set (no copies)
        {
            const int hp = (t < 14) ? (t + 2) : 15;
            h4[cur][0] = *reinterpret_cast<const f32x4*>(hbase + hp * 32);
            h4[cur][1] = *reinterpret_cast<const f32x4*>(hbase + hp * 32 + 16);
        }

        float tm = sc[0][0];
#pragma unroll
        for (int nt = 0; nt < 2; ++nt)
#pragma unroll
            for (int r = 0; r < 4; ++r) tm = fmaxf(tm, sc[nt][r]);
        tm = fmaxf(tm, __shfl_xor(tm, 16));
        tm = fmaxf(tm, __shfl_xor(tm, 32));
        float mn = fmaxf(m, tm);
        float ps = 0.0f;
#pragma unroll
        for (int nt = 0; nt < 2; ++nt)
#pragma unroll
            for (int r = 0; r < 4; ++r) ps += __expf(sc[nt][r] - mn);
        ps += __shfl_xor(ps, 16);
        ps += __shfl_xor(ps, 32);
        l = l * __expf(m - mn) + ps;
        m = mn;
    }

    if (lane < 16) {
        const int base = ((h * 128 + rb) * 4 + chunk) * 16;
        m_part[base + lane] = m;
        l_part[base + lane] = l;
    }
#undef STAGE_K2
}

// ---------------- K2b: emit — chunked, single-buffer K/V, bottom-stage pipeline ----------------
// grid 8192 x 64; LDS 9KB -> ~17 blocks/CU. Stage t+1 after lgkmcnt(0) fence; NT stores last.
__launch_bounds__(64, 4)
__global__ void attn_emit(const unsigned short* __restrict__ qb,
                          const unsigned short* __restrict__ kb,
                          const unsigned short* __restrict__ vt,
                          const float* __restrict__ hist,
                          const float* __restrict__ beta_p,
                          const float* __restrict__ m_part,
                          const float* __restrict__ l_part,
                          float* __restrict__ attn_out,
                          float* __restrict__ nh_out,
                          float* __restrict__ opart) {
    __shared__ unsigned short Kb[2048];
    __shared__ unsigned short Vb[2048];
    __shared__ unsigned short Psw[512];
    const int lane = threadIdx.x;
    const int g = lane >> 4, q15 = lane & 15;
    const int bid = blockIdx.x;
    const int orig = (bid & 7) * 1024 + (bid >> 3);
    const int h = orig >> 9;
    const int rb = (orig >> 2) & 127;
    const int chunk = orig & 3;
    const float beta = beta_p[0];
    const float scale = 0.125f;

    const unsigned short* qsrc = qb + ((size_t)h * N_TOK + rb * 16 + q15) * 64;
    bf16x8 aq0 = *reinterpret_cast<const bf16x8*>(qsrc + 8 * g);
    bf16x8 aq1 = *reinterpret_cast<const bf16x8*>(qsrc + 8 * g + 32);

    // merge per-chunk stats -> global m, inv_l for row q15
    float m_row, inv_l;
    {
        const int pbase = (h * 128 + rb) * 4 * 16;
        float m0 = m_part[pbase + 0 * 16 + q15];
        float m1 = m_part[pbase + 1 * 16 + q15];
        float m2 = m_part[pbase + 2 * 16 + q15];
        float m3 = m_part[pbase + 3 * 16 + q15];
        float mm = fmaxf(fmaxf(m0, m1), fmaxf(m2, m3));
        float ll = l_part[pbase + 0 * 16 + q15] * __expf(m0 - mm)
                 + l_part[pbase + 1 * 16 + q15] * __expf(m1 - mm)
                 + l_part[pbase + 2 * 16 + q15] * __expf(m2 - mm)
                 + l_part[pbase + 3 * 16 + q15] * __expf(m3 - mm);
        m_row = mm;
        inv_l = 1.0f / ll;
    }

    const int koff = (lane >> 3) * 64 + (((lane & 7) ^ (lane >> 3)) << 3);
    const int voff = (lane >> 2) * 32 + (((lane & 3) ^ ((lane >> 3) & 3)) << 3);
    const unsigned short* kt0 = kb + (size_t)h * N_TOK * 64;
    const unsigned short* vt0 = vt + (size_t)h * N_TOK * 64;

#define STAGE_K1(CT) do { const unsigned short* _s = kt0 + (size_t)(CT) * 2048 + koff; \
        gl_lds16(_s,        &Kb[0]);    gl_lds16(_s + 512,  &Kb[512]);   \
        gl_lds16(_s + 1024, &Kb[1024]); gl_lds16(_s + 1536, &Kb[1536]); } while (0)
#define STAGE_V1(CT) do { const unsigned short* _s = vt0 + (size_t)(CT) * 2048 + voff; \
        gl_lds16(_s,        &Vb[0]);    gl_lds16(_s + 512,  &Vb[512]);   \
        gl_lds16(_s + 1024, &Vb[1024]); gl_lds16(_s + 1536, &Vb[1536]); } while (0)

    const size_t rowbase = ((size_t)h * N_TOK + rb * 16 + q15) * N_TOK;
    const float* hbase = hist + rowbase + chunk * 512 + 4 * g;
    float* abase = attn_out + rowbase + chunk * 512 + 4 * g;
    float* nbase = nh_out + rowbase + chunk * 512 + 4 * g;
    const int ct0 = chunk * 16;

    f32x4 oacc[4];
#pragma unroll
    for (int di = 0; di < 4; ++di) oacc[di] = zero4();

    f32x4 h4[2][2];
    // prologue: stage tile 0 + hist tile 0
    STAGE_K1(ct0); STAGE_V1(ct0);
    h4[0][0] = *reinterpret_cast<const f32x4*>(hbase);
    h4[0][1] = *reinterpret_cast<const f32x4*>(hbase + 16);

#pragma unroll 2
    for (int t = 0; t < 16; ++t) {
        const int p = t & 1;
        if (t == 0) { WAITV(0); } else { WAITV(4); }  // retire stage(t)+hist(t); keep 4 NT stores

        // QK^T from Kb (swizzled reads)
        f32x4 s_acc[2];
#pragma unroll
        for (int nt = 0; nt < 2; ++nt) {
            int krow = nt * 16 + q15;
            bf16x8 kf0 = *reinterpret_cast<const bf16x8*>(Kb + krow * 64 + ((g ^ (q15 & 7)) << 3));
            bf16x8 kf1 = *reinterpret_cast<const bf16x8*>(Kb + krow * 64 + (((4 + g) ^ (q15 & 7)) << 3));
            s_acc[nt] = __builtin_amdgcn_mfma_f32_16x16x32_bf16(kf0, aq0, zero4(), 0, 0, 0);
            s_acc[nt] = __builtin_amdgcn_mfma_f32_16x16x32_bf16(kf1, aq1, s_acc[nt], 0, 0, 0);
        }

        // softmax emit (payload to regs) + P pack
        f32x4 sA[2], sN[2];
#pragma unroll
        for (int nt = 0; nt < 2; ++nt) {
            float a0 = __expf(s_acc[nt][0] * scale + beta * h4[p][nt][0] - m_row) * inv_l;
            float a1 = __expf(s_acc[nt][1] * scale + beta * h4[p][nt][1] - m_row) * inv_l;
            float a2 = __expf(s_acc[nt][2] * scale + beta * h4[p][nt][2] - m_row) * inv_l;
            float a3 = __expf(s_acc[nt][3] * scale + beta * h4[p][nt][3] - m_row) * inv_l;
            f32x4 av, nv;
            av[0] = a0; av[1] = a1; av[2] = a2; av[3] = a3;
            nv[0] = a0 + h4[p][nt][0]; nv[1] = a1 + h4[p][nt][1];
            nv[2] = a2 + h4[p][nt][2]; nv[3] = a3 + h4[p][nt][3];
            sA[nt] = av; sN[nt] = nv;
            ushort4 pp;
            pp.x = f2bf(a0); pp.y = f2bf(a1); pp.z = f2bf(a2); pp.w = f2bf(a3);
            *reinterpret_cast<ushort4*>(Psw + q15 * 32 + (((4 * nt + g) ^ (q15 & 6)) << 2)) = pp;
        }

        // PV
        {
            bf16x8 pa = *reinterpret_cast<const bf16x8*>(Psw + q15 * 32 + (((2 * g) ^ (q15 & 6)) << 2));
#pragma unroll
            for (int di = 0; di < 4; ++di) {
                int vrow = di * 16 + q15;
                bf16x8 vf = *reinterpret_cast<const bf16x8*>(Vb + vrow * 32 + ((g ^ ((q15 >> 1) & 3)) << 3));
                oacc[di] = __builtin_amdgcn_mfma_f32_16x16x32_bf16(pa, vf, oacc[di], 0, 0, 0);
            }
        }

        // bottom: fence LDS reads, then stage t+1 (single buffer is now safe), hist t+1,
        // then NT stores of tile t (newest in vmcnt queue -> next WAITV(4) keeps them).
        LGKM0();
        if (t < 15) {
            STAGE_K1(ct0 + t + 1); STAGE_V1(ct0 + t + 1);
            h4[p ^ 1][0] = *reinterpret_cast<const f32x4*>(hbase + (t + 1) * 32);
            h4[p ^ 1][1] = *reinterpret_cast<const f32x4*>(hbase + (t + 1) * 32 + 16);
        }
        __builtin_nontemporal_store(sA[0], reinterpret_cast<f32x4*>(abase + t * 32));
        __builtin_nontemporal_store(sA[1], reinterpret_cast<f32x4*>(abase + t * 32 + 16));
        __builtin_nontemporal_store(sN[0], reinterpret_cast<f32x4*>(nbase + t * 32));
        __builtin_nontemporal_store(sN[1], reinterpret_cast<f32x4*>(nbase + t * 32 + 16));
    }

    // PV partial for this chunk: opart[chunk][h][n][d]
#pragma unroll
    for (int di = 0; di < 4; ++di) {
#pragma unroll
        for (int r = 0; r < 4; ++r) {
            int rl = g * 4 + r;
            int d = di * 16 + q15;
            opart[((size_t)(chunk * NHEAD + h) * N_TOK + rb * 16 + rl) * 64 + d] = oacc[di][r];
        }
    }
#undef STAGE_K1
#undef STAGE_V1
}

// ---------------- K2c: reduce PV partials ----------------
__global__ void reduce_hv(const float4* __restrict__ op, float4* __restrict__ hv) {
    size_t i = (size_t)blockIdx.x * blockDim.x + threadIdx.x;
    const size_t C = (size_t)NHEAD * N_TOK * DHEAD / 4;
    float4 a = op[i], b = op[i + C], c = op[i + 2 * C], d = op[i + 3 * C];
    float4 r;
    r.x = a.x + b.x + c.x + d.x;
    r.y = a.y + b.y + c.y + d.y;
    r.z = a.z + b.z + c.z + d.z;
    r.w = a.w + b.w + c.w + d.w;
    hv[i] = r;
}

// ---------------- K3: output projection ----------------
__launch_bounds__(256)
__global__ void out_proj(const float* __restrict__ hv, const float* __restrict__ Wo,
                         const float* __restrict__ bo, float* __restrict__ out) {
    __shared__ float wos[64][129];
    const int tid = threadIdx.x;
    const int dd = tid & 63;
    const int w = tid >> 6;
    const int n0 = blockIdx.x * 16;
    float acc[4] = {0.f, 0.f, 0.f, 0.f};
    for (int kc = 0; kc < 1024; kc += 128) {
        __syncthreads();
#pragma unroll
        for (int i = 0; i < 32; i++) {
            int e = tid + 256 * i;
            int r = e >> 7, j = e & 127;
            wos[r][j] = Wo[(size_t)r * 1024 + kc + j];
        }
        __syncthreads();
#pragma unroll 4
        for (int k = 0; k < 128; k++) {
            float wv = wos[dd][k];
            int jg = kc + k;
            const float* hb = hv + ((size_t)(jg >> 6) * N_TOK) * 64 + (jg & 63);
#pragma unroll
            for (int q = 0; q < 4; q++) {
                acc[q] += hb[(size_t)(n0 + w + 4 * q) * 64] * wv;
            }
        }
    }
#pragma unroll
    for (int q = 0; q < 4; q++)
        out[(size_t)(n0 + w + 4 * q) * 64 + dd] = acc[q] + bo[dd];
}

extern "C" void kernel_launch(void* const* d_in, const int* in_sizes, int n_in,
                              void* d_out, int out_size, void* d_ws, size_t ws_size,
                              hipStream_t stream) {
    const float* x    = (const float*)d_in[0];
    const float* hist = (const float*)d_in[1];
    const float* Wq_w = (const float*)d_in[2];
    const float* Wq_b = (const float*)d_in[3];
    const float* Wk_w = (const float*)d_in[4];
    const float* Wk_b = (const float*)d_in[5];
    const float* Wv_w = (const float*)d_in[6];
    const float* Wv_b = (const float*)d_in[7];
    const float* Wo_w = (const float*)d_in[8];
    const float* Wo_b = (const float*)d_in[9];
    const float* beta = (const float*)d_in[10];

    float* out = (float*)d_out;
    float* attn_out = out + 131072;
    float* nh_out = attn_out + (size_t)NHEAD * N_TOK * N_TOK;

    unsigned short* xb  = (unsigned short*)d_ws;                 // 2M shorts
    unsigned short* wb  = xb + (size_t)N_TOK * HIDDEN;           // 3M shorts
    unsigned short* qb  = wb + (size_t)3 * HIDDEN * HIDDEN;      // 2M
    unsigned short* kb  = qb + (size_t)N_TOK * HIDDEN;
    unsigned short* vt  = kb + (size_t)N_TOK * HIDDEN;
    float* hvb    = (float*)(vt + (size_t)N_TOK * HIDDEN);       // 2M f32
    float* m_part = hvb + (size_t)N_TOK * HIDDEN;                // 128K f32
    float* l_part = m_part + 16 * 128 * 4 * 16;                  // 128K f32
    float* opart  = l_part + 16 * 128 * 4 * 16;                  // 8M f32 (32MB)

    cvt4_kernel<<<5120, 256, 0, stream>>>(x, Wq_w, Wk_w, Wv_w, xb);
    gemm_qkv<<<dim3(24, 16), 256, 0, stream>>>(xb, wb, Wq_b, Wk_b, Wv_b, qb, kb, vt);
    attn_stats<<<8192, 64, 0, stream>>>(qb, kb, hist, beta, m_part, l_part);
    attn_emit<<<8192, 64, 0, stream>>>(qb, kb, vt, hist, beta, m_part, l_part,
                                       attn_out, nh_out, opart);
    reduce_hv<<<2048, 256, 0, stream>>>((const float4*)opart, (float4*)hvb);
    out_proj<<<128, 256, 0, stream>>>(hvb, Wo_w, Wo_b, out);
}

// Round 12
// 519.987 us; speedup vs baseline: 1.0428x; 1.0428x over previous
//
#include <hip/hip_runtime.h>
#include <hip/hip_bf16.h>

#define N_TOK 2048
#define HIDDEN 1024
#define NHEAD 16
#define DHEAD 64

typedef __attribute__((ext_vector_type(8))) short bf16x8;
typedef __attribute__((ext_vector_type(4))) float f32x4;

#define WAITV(N) do { asm volatile("s_waitcnt vmcnt(" #N ")" ::: "memory"); \
                      __builtin_amdgcn_sched_barrier(0); } while (0)
#define LGKM0() do { asm volatile("s_waitcnt lgkmcnt(0)" ::: "memory"); \
                     __builtin_amdgcn_sched_barrier(0); } while (0)

__device__ inline unsigned short f2bf(float x) {
    __hip_bfloat16 h = __float2bfloat16(x);
    return *reinterpret_cast<unsigned short*>(&h);
}

__device__ inline f32x4 zero4() {
    f32x4 z;
    z[0] = 0.f; z[1] = 0.f; z[2] = 0.f; z[3] = 0.f;
    return z;
}

// async global->LDS, 16B per lane; dest = uniform base + lane*16
__device__ inline void gl_lds16(const unsigned short* g, unsigned short* l) {
    __builtin_amdgcn_global_load_lds(
        (const __attribute__((address_space(1))) unsigned int*)g,
        (__attribute__((address_space(3))) unsigned int*)l, 16, 0, 0);
}

// ---------------- K0: fused f32 -> bf16 conversion for x, Wq, Wk, Wv ----------------
__global__ void cvt4_kernel(const float* __restrict__ x, const float* __restrict__ wq,
                            const float* __restrict__ wk, const float* __restrict__ wv,
                            unsigned short* __restrict__ dst) {
    int i = blockIdx.x * blockDim.x + threadIdx.x;  // 1310720 float4 jobs
    const float* src;
    int off;
    if (i < 524288)       { src = x;  off = i; }
    else if (i < 786432)  { src = wq; off = i - 524288; }
    else if (i < 1048576) { src = wk; off = i - 786432; }
    else                  { src = wv; off = i - 1048576; }
    float4 v = reinterpret_cast<const float4*>(src)[off];
    ushort4 o;
    o.x = f2bf(v.x); o.y = f2bf(v.y); o.z = f2bf(v.z); o.w = f2bf(v.w);
    reinterpret_cast<ushort4*>(dst)[i] = o;
}

// ---------------- K1: fused QKV GEMM; v-region writes tiled vt directly ----------------
__launch_bounds__(256)
__global__ void gemm_qkv(const unsigned short* __restrict__ xb,
                         const unsigned short* __restrict__ wb,
                         const float* __restrict__ bq, const float* __restrict__ bk,
                         const float* __restrict__ bv,
                         unsigned short* __restrict__ qb, unsigned short* __restrict__ kb,
                         unsigned short* __restrict__ vt) {
    __shared__ unsigned short As[2][128 * 64];
    __shared__ unsigned short Bs[2][128 * 64];
    const int tid = threadIdx.x;
    const int lane = tid & 63;
    const int w = tid >> 6;
    const int wr = w >> 1, wc = w & 1;
    const int rb = blockIdx.y * 128;
    const int cb = blockIdx.x * 128;
    const int r0 = tid >> 3, c0 = tid & 7;

    f32x4 acc[4][4];
    for (int i = 0; i < 4; i++)
        for (int j = 0; j < 4; j++) acc[i][j] = zero4();

    uint4 va[4], vb4[4];
#pragma unroll
    for (int i = 0; i < 4; i++) {
        va[i]  = *reinterpret_cast<const uint4*>(xb + (size_t)(rb + r0 + 32 * i) * HIDDEN + c0 * 8);
        vb4[i] = *reinterpret_cast<const uint4*>(wb + (size_t)(cb + r0 + 32 * i) * HIDDEN + c0 * 8);
    }
#pragma unroll
    for (int i = 0; i < 4; i++) {
        int row = r0 + 32 * i;
        *reinterpret_cast<uint4*>(As[0] + row * 64 + ((c0 ^ (row & 7)) << 3)) = va[i];
        *reinterpret_cast<uint4*>(Bs[0] + row * 64 + ((c0 ^ (row & 7)) << 3)) = vb4[i];
    }
    __syncthreads();
    int cur = 0;

    for (int kt = 0; kt < 16; ++kt) {
        if (kt < 15) {
#pragma unroll
            for (int i = 0; i < 4; i++) {
                va[i]  = *reinterpret_cast<const uint4*>(xb + (size_t)(rb + r0 + 32 * i) * HIDDEN + (kt + 1) * 64 + c0 * 8);
                vb4[i] = *reinterpret_cast<const uint4*>(wb + (size_t)(cb + r0 + 32 * i) * HIDDEN + (kt + 1) * 64 + c0 * 8);
            }
        }
#pragma unroll
        for (int kk = 0; kk < 2; kk++) {
            bf16x8 a[4], b[4];
#pragma unroll
            for (int mi = 0; mi < 4; mi++) {
                int row = wr * 64 + mi * 16 + (lane & 15);
                a[mi] = *reinterpret_cast<const bf16x8*>(As[cur] + row * 64 + (((kk * 4 + (lane >> 4)) ^ (row & 7)) << 3));
            }
#pragma unroll
            for (int ni = 0; ni < 4; ni++) {
                int row = wc * 64 + ni * 16 + (lane & 15);
                b[ni] = *reinterpret_cast<const bf16x8*>(Bs[cur] + row * 64 + (((kk * 4 + (lane >> 4)) ^ (row & 7)) << 3));
            }
#pragma unroll
            for (int mi = 0; mi < 4; mi++)
#pragma unroll
                for (int ni = 0; ni < 4; ni++)
                    acc[mi][ni] = __builtin_amdgcn_mfma_f32_16x16x32_bf16(a[mi], b[ni], acc[mi][ni], 0, 0, 0);
        }
        if (kt < 15) {
#pragma unroll
            for (int i = 0; i < 4; i++) {
                int row = r0 + 32 * i;
                *reinterpret_cast<uint4*>(As[cur ^ 1] + row * 64 + ((c0 ^ (row & 7)) << 3)) = va[i];
                *reinterpret_cast<uint4*>(Bs[cur ^ 1] + row * 64 + ((c0 ^ (row & 7)) << 3)) = vb4[i];
            }
        }
        __syncthreads();
        cur ^= 1;
    }

    const int region = blockIdx.x >> 3;  // 0=q, 1=k, 2=v
    const float* bias = region == 0 ? bq : (region == 1 ? bk : bv);
    unsigned short* dst = region == 0 ? qb : kb;
#pragma unroll
    for (int mi = 0; mi < 4; mi++) {
#pragma unroll
        for (int ni = 0; ni < 4; ni++) {
            int colg = cb + wc * 64 + ni * 16 + (lane & 15);
            int jj = colg & 1023;
            int hh = jj >> 6, d = jj & 63;
            float bval = bias[jj];
#pragma unroll
            for (int r = 0; r < 4; r++) {
                int n = rb + wr * 64 + mi * 16 + ((lane >> 4) << 2) + r;
                unsigned short val = f2bf(acc[mi][ni][r] + bval);
                if (region < 2)
                    dst[((size_t)hh * N_TOK + n) * 64 + d] = val;
                else  // v: tiled layout vt[((h*64 + n/32)*64 + d)*32 + n%32]
                    vt[(((size_t)(hh * 64 + (n >> 5)) * 64 + d) * 32) + (n & 31)] = val;
            }
        }
    }
}

// ---------------- K2: fused attention — 9KB LDS, 16 waves/CU, counted-vmcnt pipeline ----------------
// Pass 1: K double-buffered across KV[0]/KV[1] (WAITV(6) ledger).
// Pass 2: K in KV[0], V in KV[1], single-buffered; bottom-stage after LGKM0; NT stores last.
__launch_bounds__(64, 4)
__global__ void attn_fused(const unsigned short* __restrict__ qb,
                           const unsigned short* __restrict__ kb,
                           const unsigned short* __restrict__ vt,
                           const float* __restrict__ hist,
                           const float* __restrict__ beta_p,
                           float* __restrict__ attn_out,
                           float* __restrict__ nh_out,
                           float* __restrict__ hv) {
    __shared__ unsigned short KV[2][2048];
    __shared__ unsigned short Psw[512];
    const int lane = threadIdx.x;
    const int g = lane >> 4, q15 = lane & 15;
    // XCD swizzle: each XCD gets 2 consecutive heads
    const int bid = blockIdx.x;
    const int orig = (bid & 7) * 256 + (bid >> 3);
    const int h = orig >> 7, rb = orig & 127;
    const float beta = beta_p[0];
    const float scale = 0.125f;

    const unsigned short* qsrc = qb + ((size_t)h * N_TOK + rb * 16 + q15) * 64;
    bf16x8 aq0 = *reinterpret_cast<const bf16x8*>(qsrc + 8 * g);
    bf16x8 aq1 = *reinterpret_cast<const bf16x8*>(qsrc + 8 * g + 32);

    // staging: linear LDS dest; inverse-swizzled per-lane SOURCE (rule #21)
    const int koff = (lane >> 3) * 64 + (((lane & 7) ^ (lane >> 3)) << 3);          // shorts
    const int voff = (lane >> 2) * 32 + (((lane & 3) ^ ((lane >> 3) & 3)) << 3);    // shorts
    const unsigned short* kt0 = kb + (size_t)h * N_TOK * 64;  // + t*2048
    const unsigned short* vt0 = vt + (size_t)h * N_TOK * 64;  // + t*2048 (pre-tiled [t][d][32])

#define STAGE_K(T, B) do { const unsigned short* _s = kt0 + (size_t)(T) * 2048 + koff; \
        gl_lds16(_s,        &KV[B][0]);    gl_lds16(_s + 512,  &KV[B][512]);   \
        gl_lds16(_s + 1024, &KV[B][1024]); gl_lds16(_s + 1536, &KV[B][1536]); } while (0)
#define STAGE_V(T, B) do { const unsigned short* _s = vt0 + (size_t)(T) * 2048 + voff; \
        gl_lds16(_s,        &KV[B][0]);    gl_lds16(_s + 512,  &KV[B][512]);   \
        gl_lds16(_s + 1024, &KV[B][1024]); gl_lds16(_s + 1536, &KV[B][1536]); } while (0)

    const size_t rowbase = ((size_t)h * N_TOK + rb * 16 + q15) * N_TOK;
    const float* hbase = hist + rowbase + 4 * g;
    float* abase = attn_out + rowbase + 4 * g;
    float* nbase = nh_out + rowbase + 4 * g;

    float m = -1e30f, l = 0.0f;
    f32x4 h4[2];

    // ---- pass 1 prologue: stage K(0)->KV[0], hist(0) ----
    STAGE_K(0, 0);
    h4[0] = *reinterpret_cast<const f32x4*>(hbase);
    h4[1] = *reinterpret_cast<const f32x4*>(hbase + 16);

    // ---- pass 1: stats (K dbuf across KV[0]/KV[1]) ----
    for (int t = 0; t < 64; ++t) {
        const int cur = t & 1;
        if (t < 63) {
            STAGE_K(t + 1, cur ^ 1);
            WAITV(6);   // retire stage(t); keep stage(t+1) 4 + hist(t) 2 tracked by compiler
        } else {
            WAITV(0);
        }
        f32x4 s_acc[2];
#pragma unroll
        for (int nt = 0; nt < 2; ++nt) {
            int krow = nt * 16 + q15;
            bf16x8 kf0 = *reinterpret_cast<const bf16x8*>(KV[cur] + krow * 64 + ((g ^ (q15 & 7)) << 3));
            bf16x8 kf1 = *reinterpret_cast<const bf16x8*>(KV[cur] + krow * 64 + (((4 + g) ^ (q15 & 7)) << 3));
            s_acc[nt] = __builtin_amdgcn_mfma_f32_16x16x32_bf16(kf0, aq0, zero4(), 0, 0, 0);
            s_acc[nt] = __builtin_amdgcn_mfma_f32_16x16x32_bf16(kf1, aq1, s_acc[nt], 0, 0, 0);
        }
        float sc[2][4];
#pragma unroll
        for (int nt = 0; nt < 2; ++nt)
#pragma unroll
            for (int r = 0; r < 4; ++r)
                sc[nt][r] = s_acc[nt][r] * scale + beta * h4[nt][r];

        // h4 consumed -> reload directly with hist(t+1) (no copy, no forced wait here)
        if (t < 63) {
            h4[0] = *reinterpret_cast<const f32x4*>(hbase + (t + 1) * 32);
            h4[1] = *reinterpret_cast<const f32x4*>(hbase + (t + 1) * 32 + 16);
        }

        float tm = sc[0][0];
#pragma unroll
        for (int nt = 0; nt < 2; ++nt)
#pragma unroll
            for (int r = 0; r < 4; ++r) tm = fmaxf(tm, sc[nt][r]);
        tm = fmaxf(tm, __shfl_xor(tm, 16));
        tm = fmaxf(tm, __shfl_xor(tm, 32));
        float mn = fmaxf(m, tm);
        float ps = 0.0f;
#pragma unroll
        for (int nt = 0; nt < 2; ++nt)
#pragma unroll
            for (int r = 0; r < 4; ++r) ps += __expf(sc[nt][r] - mn);
        ps += __shfl_xor(ps, 16);
        ps += __shfl_xor(ps, 32);
        l = l * __expf(m - mn) + ps;
        m = mn;
    }
    const float inv_l = 1.0f / l;

    f32x4 oacc[4];
#pragma unroll
    for (int di = 0; di < 4; ++di) oacc[di] = zero4();

    // ---- pass 2 prologue: restage K(63)->KV[0], V(63)->KV[1], hist(63) ----
    STAGE_K(63, 0);
    STAGE_V(63, 1);
    h4[0] = *reinterpret_cast<const f32x4*>(hbase + 63 * 32);
    h4[1] = *reinterpret_cast<const f32x4*>(hbase + 63 * 32 + 16);

    // ---- pass 2: emit attn/nh + PV (reverse order for L2/L3 hist reuse) ----
    for (int tt = 0; tt < 64; ++tt) {
        const int t = 63 - tt;
        if (tt == 0) { WAITV(0); } else { WAITV(4); }  // retire hist(t)+stage(t); keep 4 NT stores

        // QK^T from KV[0]
        f32x4 s_acc[2];
#pragma unroll
        for (int nt = 0; nt < 2; ++nt) {
            int krow = nt * 16 + q15;
            bf16x8 kf0 = *reinterpret_cast<const bf16x8*>(KV[0] + krow * 64 + ((g ^ (q15 & 7)) << 3));
            bf16x8 kf1 = *reinterpret_cast<const bf16x8*>(KV[0] + krow * 64 + (((4 + g) ^ (q15 & 7)) << 3));
            s_acc[nt] = __builtin_amdgcn_mfma_f32_16x16x32_bf16(kf0, aq0, zero4(), 0, 0, 0);
            s_acc[nt] = __builtin_amdgcn_mfma_f32_16x16x32_bf16(kf1, aq1, s_acc[nt], 0, 0, 0);
        }

        // softmax emit (payload to regs) + P pack
        f32x4 sA[2], sN[2];
#pragma unroll
        for (int nt = 0; nt < 2; ++nt) {
            float a0 = __expf(s_acc[nt][0] * scale + beta * h4[nt][0] - m) * inv_l;
            float a1 = __expf(s_acc[nt][1] * scale + beta * h4[nt][1] - m) * inv_l;
            float a2 = __expf(s_acc[nt][2] * scale + beta * h4[nt][2] - m) * inv_l;
            float a3 = __expf(s_acc[nt][3] * scale + beta * h4[nt][3] - m) * inv_l;
            f32x4 av, nv;
            av[0] = a0; av[1] = a1; av[2] = a2; av[3] = a3;
            nv[0] = a0 + h4[nt][0]; nv[1] = a1 + h4[nt][1];
            nv[2] = a2 + h4[nt][2]; nv[3] = a3 + h4[nt][3];
            sA[nt] = av; sN[nt] = nv;
            ushort4 pp;
            pp.x = f2bf(a0); pp.y = f2bf(a1); pp.z = f2bf(a2); pp.w = f2bf(a3);
            *reinterpret_cast<ushort4*>(Psw + q15 * 32 + (((4 * nt + g) ^ (q15 & 6)) << 2)) = pp;
        }

        // h4 consumed -> reload hist(t-1) (oldest entries in queue for next WAITV)
        if (tt < 63) {
            h4[0] = *reinterpret_cast<const f32x4*>(hbase + (t - 1) * 32);
            h4[1] = *reinterpret_cast<const f32x4*>(hbase + (t - 1) * 32 + 16);
        }

        // PV from KV[1]
        {
            bf16x8 pa = *reinterpret_cast<const bf16x8*>(Psw + q15 * 32 + (((2 * g) ^ (q15 & 6)) << 2));
#pragma unroll
            for (int di = 0; di < 4; ++di) {
                int vrow = di * 16 + q15;
                bf16x8 vf = *reinterpret_cast<const bf16x8*>(KV[1] + vrow * 32 + ((g ^ ((q15 >> 1) & 3)) << 3));
                oacc[di] = __builtin_amdgcn_mfma_f32_16x16x32_bf16(pa, vf, oacc[di], 0, 0, 0);
            }
        }

        // bottom: fence all LDS ops of this tile, then single-buffer restage, then NT stores (newest)
        LGKM0();
        if (tt < 63) {
            STAGE_K(t - 1, 0);
            STAGE_V(t - 1, 1);
        }
        __builtin_nontemporal_store(sA[0], reinterpret_cast<f32x4*>(abase + t * 32));
        __builtin_nontemporal_store(sA[1], reinterpret_cast<f32x4*>(abase + t * 32 + 16));
        __builtin_nontemporal_store(sN[0], reinterpret_cast<f32x4*>(nbase + t * 32));
        __builtin_nontemporal_store(sN[1], reinterpret_cast<f32x4*>(nbase + t * 32 + 16));
    }

    // epilogue: hv write (complete over all cols)
#pragma unroll
    for (int di = 0; di < 4; ++di) {
#pragma unroll
        for (int r = 0; r < 4; ++r) {
            int rl = g * 4 + r;
            int d = di * 16 + q15;
            hv[((size_t)h * N_TOK + rb * 16 + rl) * 64 + d] = oacc[di][r];
        }
    }
#undef STAGE_K
#undef STAGE_V
}

// ---------------- K3: output projection ----------------
__launch_bounds__(256)
__global__ void out_proj(const float* __restrict__ hv, const float* __restrict__ Wo,
                         const float* __restrict__ bo, float* __restrict__ out) {
    __shared__ float wos[64][129];
    const int tid = threadIdx.x;
    const int dd = tid & 63;
    const int w = tid >> 6;
    const int n0 = blockIdx.x * 16;
    float acc[4] = {0.f, 0.f, 0.f, 0.f};
    for (int kc = 0; kc < 1024; kc += 128) {
        __syncthreads();
#pragma unroll
        for (int i = 0; i < 32; i++) {
            int e = tid + 256 * i;
            int r = e >> 7, j = e & 127;
            wos[r][j] = Wo[(size_t)r * 1024 + kc + j];
        }
        __syncthreads();
#pragma unroll 4
        for (int k = 0; k < 128; k++) {
            float wv = wos[dd][k];
            int jg = kc + k;
            const float* hb = hv + ((size_t)(jg >> 6) * N_TOK) * 64 + (jg & 63);
#pragma unroll
            for (int q = 0; q < 4; q++) {
                acc[q] += hb[(size_t)(n0 + w + 4 * q) * 64] * wv;
            }
        }
    }
#pragma unroll
    for (int q = 0; q < 4; q++)
        out[(size_t)(n0 + w + 4 * q) * 64 + dd] = acc[q] + bo[dd];
}

extern "C" void kernel_launch(void* const* d_in, const int* in_sizes, int n_in,
                              void* d_out, int out_size, void* d_ws, size_t ws_size,
                              hipStream_t stream) {
    const float* x    = (const float*)d_in[0];
    const float* hist = (const float*)d_in[1];
    const float* Wq_w = (const float*)d_in[2];
    const float* Wq_b = (const float*)d_in[3];
    const float* Wk_w = (const float*)d_in[4];
    const float* Wk_b = (const float*)d_in[5];
    const float* Wv_w = (const float*)d_in[6];
    const float* Wv_b = (const float*)d_in[7];
    const float* Wo_w = (const float*)d_in[8];
    const float* Wo_b = (const float*)d_in[9];
    const float* beta = (const float*)d_in[10];

    float* out = (float*)d_out;
    float* attn_out = out + 131072;
    float* nh_out = attn_out + (size_t)NHEAD * N_TOK * N_TOK;

    unsigned short* xb  = (unsigned short*)d_ws;                 // 2M shorts
    unsigned short* wb  = xb + (size_t)N_TOK * HIDDEN;           // 3M shorts
    unsigned short* qb  = wb + (size_t)3 * HIDDEN * HIDDEN;      // 2M
    unsigned short* kb  = qb + (size_t)N_TOK * HIDDEN;
    unsigned short* vt  = kb + (size_t)N_TOK * HIDDEN;
    float* hvb = (float*)(vt + (size_t)N_TOK * HIDDEN);          // 2M f32

    cvt4_kernel<<<5120, 256, 0, stream>>>(x, Wq_w, Wk_w, Wv_w, xb);
    gemm_qkv<<<dim3(24, 16), 256, 0, stream>>>(xb, wb, Wq_b, Wk_b, Wv_b, qb, kb, vt);
    attn_fused<<<2048, 64, 0, stream>>>(qb, kb, vt, hist, beta, attn_out, nh_out, hvb);
    out_proj<<<128, 256, 0, stream>>>(hvb, Wo_w, Wo_b, out);
}